// Round 13
// baseline (185.705 us; speedup 1.0000x reference)
//
#include <hip/hip_runtime.h>
#include <stdint.h>

// Problem constants
#define D_DIM 512
#define B_ROWS 4096
#define N_ROWS 8192
// (1/TEMPERATURE) * log2(e) : exp(x/T) == exp2(x * SCALE_L2E)
#define SCALE_L2E 14.426950408889634f

#define NKB 4                       // K-blocks of 128 (one 16x16x128 MFMA step each)
// 64-row tiles: 128 of them. Supers of 16 tiles (8 supers of 1024 rows).
// Super-pairs (SI<=SJ): 36. Sub-pairs: diag super = 136, off-diag = 256.
// Total blocks = 28*256 + 8*136 = 8256 = 8 * 1032 (bijective XCD swizzle).
#define NBLK 8256

typedef __attribute__((ext_vector_type(4))) float f32x4;
typedef __attribute__((ext_vector_type(8))) int i32x8;   // 32 fp8 bytes = 8 VGPRs
#define SCALE1 0x7F7F7F7F                                // E8M0 1.0 in every byte

// ---------------- K1: normalize rows -> fp8 e4m3 Zn (kb-tiled), fp32 pos -------------------
// Zn layout: [kb=0..3][row=0..8191][128 B] (plane = 1 MiB, total 4 MiB).
// MFMA 16x16x128 fragment: lane (lhi,l15) holds row l15, k = lhi*32..+32 -> reads its 32 B
// contiguously at row*128 + lhi*32 (2 x dwordx4, perfectly coalesced per 16-lane group).
__global__ __launch_bounds__(256) void k_normalize(const float* __restrict__ zi,
                                                   const float* __restrict__ zj,
                                                   unsigned char* __restrict__ Zn,
                                                   float* __restrict__ pos) {
    const int t = threadIdx.x;
    const int lane = t & 63;
    const int i = blockIdx.x * 4 + (t >> 6);
    const float* pa = zi + (size_t)i * D_DIM + lane * 8;
    const float* pb = zj + (size_t)i * D_DIM + lane * 8;
    const float4 a0 = *(const float4*)pa;
    const float4 a1 = *(const float4*)(pa + 4);
    const float4 b0 = *(const float4*)pb;
    const float4 b1 = *(const float4*)(pb + 4);
    float ssi = a0.x*a0.x + a0.y*a0.y + a0.z*a0.z + a0.w*a0.w
              + a1.x*a1.x + a1.y*a1.y + a1.z*a1.z + a1.w*a1.w;
    float ssj = b0.x*b0.x + b0.y*b0.y + b0.z*b0.z + b0.w*b0.w
              + b1.x*b1.x + b1.y*b1.y + b1.z*b1.z + b1.w*b1.w;
    float dt  = a0.x*b0.x + a0.y*b0.y + a0.z*b0.z + a0.w*b0.w
              + a1.x*b1.x + a1.y*b1.y + a1.z*b1.z + a1.w*b1.w;
    #pragma unroll
    for (int off = 1; off < 64; off <<= 1) {
        ssi += __shfl_xor(ssi, off);
        ssj += __shfl_xor(ssj, off);
        dt  += __shfl_xor(dt,  off);
    }
    const float si = 1.0f / fmaxf(sqrtf(ssi), 1e-12f);
    const float sj = 1.0f / fmaxf(sqrtf(ssj), 1e-12f);
    // pack 8 normalized values (k = lane*8 .. +8) -> 8 fp8 e4m3 (HW RNE)
    uint2 pi8, pj8;
    {
        int w0 = 0, w1 = 0;
        w0 = __builtin_amdgcn_cvt_pk_fp8_f32(a0.x * si, a0.y * si, w0, false);
        w0 = __builtin_amdgcn_cvt_pk_fp8_f32(a0.z * si, a0.w * si, w0, true);
        w1 = __builtin_amdgcn_cvt_pk_fp8_f32(a1.x * si, a1.y * si, w1, false);
        w1 = __builtin_amdgcn_cvt_pk_fp8_f32(a1.z * si, a1.w * si, w1, true);
        pi8.x = (unsigned)w0; pi8.y = (unsigned)w1;
        w0 = 0; w1 = 0;
        w0 = __builtin_amdgcn_cvt_pk_fp8_f32(b0.x * sj, b0.y * sj, w0, false);
        w0 = __builtin_amdgcn_cvt_pk_fp8_f32(b0.z * sj, b0.w * sj, w0, true);
        w1 = __builtin_amdgcn_cvt_pk_fp8_f32(b1.x * sj, b1.y * sj, w1, false);
        w1 = __builtin_amdgcn_cvt_pk_fp8_f32(b1.z * sj, b1.w * sj, w1, true);
        pj8.x = (unsigned)w0; pj8.y = (unsigned)w1;
    }
    // lane covers k = lane*8..+7 -> kb = lane>>4, byte offset in 128B row = (lane&15)*8
    const size_t PLANE = (size_t)N_ROWS * 128;  // bytes per kb-plane
    const size_t off0 = (size_t)(lane >> 4) * PLANE + (lane & 15) * 8;
    *(uint2*)(Zn + off0 + (size_t)i * 128) = pi8;
    *(uint2*)(Zn + off0 + (size_t)(B_ROWS + i) * 128) = pj8;
    if (lane == 0) pos[i] = 20.0f * dt * si * sj;  // positive logit counted twice: 2*dot/T
}

// ---------------- K2: symmetric fused S = Zn·Zn^T (MX fp8 K=128 MFMA) + row sum(exp) ------
// ONE WAVE per block, 64x64 tile pair (I<=J over 64-row tiles), supertiled enumeration
// (supers of 16 -> 1 MiB L2-resident working set per super-pair). NO LDS, no barriers.
// Per kb (K=128): load 4 B-frags (held, 32 VGPR) + stream A-frags 2-deep (16 VGPR),
// 16 x mfma_scale_f32_16x16x128_f8f6f4 with uniform scale 1.0 (numerically == plain fp8).
// Total regs ~ acc 64 + B 32 + A 16 + addr ~= 124 <= 128 -> 4 waves/SIMD.
__global__ __launch_bounds__(64, 4) void k_gemm_lse(const unsigned char* __restrict__ Zn,
                                                    float* __restrict__ rowsum_g) {
    const int lane = threadIdx.x & 63;
    const int l15  = lane & 15, lhi = lane >> 4;

    // XCD-aware swizzle (bijective: NBLK % 8 == 0)
    int g = (blockIdx.x & 7) * (NBLK / 8) + (blockIdx.x >> 3);
    // super-pair decode (SI<=SJ, sizes 136 diag / 256 off-diag)
    int SI = 0, SJ = 0;
    {
        bool found = false;
        for (SI = 0; SI < 8 && !found; ++SI) {
            for (SJ = SI; SJ < 8; ++SJ) {
                const int sz = (SI == SJ) ? 136 : 256;
                if (g < sz) { found = true; break; }
                g -= sz;
            }
        }
        --SI;  // loop increments past the found value
    }
    int di, dj;
    if (SI == SJ) {
        di = 0;
        while (g >= 16 - di) { g -= 16 - di; ++di; }
        dj = di + g;
    } else {
        di = g >> 4; dj = g & 15;
    }
    const int I = SI * 16 + di, J = SJ * 16 + dj;
    const bool dg = (I == J);
    const int rowB = I * 64;               // wave's first output row
    const int colB = J * 64;               // wave's first output col

    const char* Zb = (const char*)Zn;
    const size_t PLANE = (size_t)N_ROWS * 128;  // bytes per kb-plane

    // fragment base pointers: lane (lhi,l15) reads row (base + l15 + 16*frag), k-seg lhi*32
    const char* pA = Zb + ((size_t)(rowB + l15)) * 128 + lhi * 32;
    const char* pB = Zb + ((size_t)(colB + l15)) * 128 + lhi * 32;

    f32x4 acc[4][4];
    #pragma unroll
    for (int a = 0; a < 4; ++a)
        #pragma unroll
        for (int b = 0; b < 4; ++b)
            #pragma unroll
            for (int q = 0; q < 4; ++q) acc[a][b][q] = 0.0f;

    #pragma unroll
    for (int kb = 0; kb < NKB; ++kb) {
        const char* _a = pA + (size_t)kb * PLANE;
        const char* _b = pB + (size_t)kb * PLANE;
        i32x8 bg[4];
        #pragma unroll
        for (int ni = 0; ni < 4; ++ni) bg[ni] = *(const i32x8*)(_b + ni * 2048);
        i32x8 af[2];
        af[0] = *(const i32x8*)(_a);
        #pragma unroll
        for (int mi = 0; mi < 4; ++mi) {
            if (mi < 3) af[(mi + 1) & 1] = *(const i32x8*)(_a + (mi + 1) * 2048);
            __builtin_amdgcn_s_setprio(1);
            #pragma unroll
            for (int ni = 0; ni < 4; ++ni)
                acc[mi][ni] = __builtin_amdgcn_mfma_scale_f32_16x16x128_f8f6f4(
                    af[mi & 1], bg[ni], acc[mi][ni],
                    0 /*A fmt: fp8 e4m3*/, 0 /*B fmt: fp8 e4m3*/,
                    0, SCALE1, 0, SCALE1);
            __builtin_amdgcn_s_setprio(0);
        }
    }

    // epilogue: e = exp2(S * 10*log2e); C/D layout: col=lane&15, row=(lane>>4)*4+reg
    float colsum[4] = {0.0f, 0.0f, 0.0f, 0.0f};
    #pragma unroll
    for (int mi = 0; mi < 4; ++mi) {
        const int growb = rowB + mi * 16 + lhi * 4;
        float rs[4] = {0.0f, 0.0f, 0.0f, 0.0f};
        if (dg) {
            #pragma unroll
            for (int ni = 0; ni < 4; ++ni) {
                const int gcol = colB + ni * 16 + l15;
                #pragma unroll
                for (int r = 0; r < 4; ++r) {
                    float arg = acc[mi][ni][r] * SCALE_L2E;
                    if (growb + r == gcol) arg = -1e30f;  // diagonal mask -> exp2 = 0
                    rs[r] += exp2f(arg);
                }
            }
        } else {
            #pragma unroll
            for (int ni = 0; ni < 4; ++ni)
                #pragma unroll
                for (int r = 0; r < 4; ++r) {
                    const float e = exp2f(acc[mi][ni][r] * SCALE_L2E);
                    rs[r] += e;
                    colsum[ni] += e;
                }
        }
        // row sums: reduce the 16 lanes sharing lhi; one atomic per (mi, r)
        #pragma unroll
        for (int r = 0; r < 4; ++r) {
            float v = rs[r];
            v += __shfl_xor(v, 1);
            v += __shfl_xor(v, 2);
            v += __shfl_xor(v, 4);
            v += __shfl_xor(v, 8);
            if (l15 == 0) atomicAdd(&rowsum_g[growb + r], v);
        }
    }
    if (!dg) {
        // column sums (symmetry): reduce across lhi groups; lanes lhi==0 hold col l15
        #pragma unroll
        for (int ni = 0; ni < 4; ++ni) {
            float c = colsum[ni];
            c += __shfl_xor(c, 16);
            c += __shfl_xor(c, 32);
            if (lhi == 0)
                atomicAdd(&rowsum_g[colB + ni * 16 + l15], c);
        }
    }
}

// ---------------- K3: loss = mean(ln(rowsum)) - mean(pos), single block ----------------
__global__ __launch_bounds__(1024) void k_finalize(const float* __restrict__ rowsum_g,
                                                   const float* __restrict__ pos,
                                                   float* __restrict__ out) {
    const int t = threadIdx.x;
    float l = 0.0f, p = 0.0f;
    #pragma unroll
    for (int q = 0; q < N_ROWS / 1024; ++q) l += logf(rowsum_g[t + q * 1024]);
    #pragma unroll
    for (int q = 0; q < B_ROWS / 1024; ++q) p += pos[t + q * 1024];
    #pragma unroll
    for (int off = 1; off < 64; off <<= 1) {
        l += __shfl_xor(l, off);
        p += __shfl_xor(p, off);
    }
    __shared__ float red[2][16];
    if ((t & 63) == 0) { red[0][t >> 6] = l; red[1][t >> 6] = p; }
    __syncthreads();
    if (t == 0) {
        float L = 0.0f, P = 0.0f;
        #pragma unroll
        for (int q = 0; q < 16; ++q) { L += red[0][q]; P += red[1][q]; }
        out[0] = (L - P) * (1.0f / (float)N_ROWS);
    }
}

extern "C" void kernel_launch(void* const* d_in, const int* in_sizes, int n_in,
                              void* d_out, int out_size, void* d_ws, size_t ws_size,
                              hipStream_t stream) {
    (void)in_sizes; (void)n_in; (void)out_size; (void)ws_size;
    const float* zi = (const float*)d_in[0];
    const float* zj = (const float*)d_in[1];

    // workspace layout
    const size_t ZN_BYTES = (size_t)N_ROWS * D_DIM;  // 4 MiB fp8 (kb-tiled)
    unsigned char* Zn     = (unsigned char*)d_ws;
    float* rowsum_g       = (float*)((char*)d_ws + ZN_BYTES);              // 8192 f32
    float* pos            = (float*)((char*)d_ws + ZN_BYTES + N_ROWS * 4); // 4096 f32

    // zero the atomically-accumulated rowsums
    hipMemsetAsync(rowsum_g, 0, N_ROWS * 4, stream);

    k_normalize<<<B_ROWS / 4, 256, 0, stream>>>(zi, zj, Zn, pos);
    k_gemm_lse<<<NBLK, 64, 0, stream>>>(Zn, rowsum_g);
    k_finalize<<<1, 1024, 0, stream>>>(rowsum_g, pos, (float*)d_out);
}

// Round 14
// 60.760 us; speedup vs baseline: 3.0564x; 3.0564x over previous
//
#include <hip/hip_runtime.h>
#include <stdint.h>

// Problem constants
#define D_DIM 512
#define B_ROWS 4096
#define N_ROWS 8192
// (1/TEMPERATURE) * log2(e) : exp(x/T) == exp2(x * SCALE_L2E)
#define SCALE_L2E 14.426950408889634f

#define NHP 8                       // K-blocks of 64 (each = two K=32 MFMA steps)
// 64-row tiles: 128. Supers of 16 tiles (8 supers of 1024 rows).
// Off-diag super-pairs (SI<SJ): 28, 256 blocks each, first (7168 slots, 256-aligned).
// Diag supers: 8, padded to 160 slots each (136 used), appended (starts 32-aligned).
// NBLK = 7168 + 1280 = 8448 = 8 * 1056; 1056 % 32 == 0 -> every XCD chunk and super
// start is 32-aligned, so each CU sees a FIXED r = s%32 within any off-diag super.
#define NOFF (28 * 256)
#define NBLK (NOFF + 8 * 160)

typedef __attribute__((ext_vector_type(4))) float f32x4;
typedef __attribute__((ext_vector_type(2))) long f8x16;  // 16 fp8 bytes = dwordx4

// ---------------- K1: normalize rows -> fp8 e4m3 Zn (hp-interleaved), fp32 pos -------------
// Zn layout: [hp=0..7][row=0..8191][64 B]; byte slot lhi*16 holds k-octet (64hp+lhi*8..+8)
// and slot lhi*16+8 holds (64hp+32+lhi*8..+8) => one dwordx4 fragment load provides the
// MFMA A/B operands for BOTH K=32 steps of the hp.
__global__ __launch_bounds__(256) void k_normalize(const float* __restrict__ zi,
                                                   const float* __restrict__ zj,
                                                   unsigned char* __restrict__ Zn,
                                                   float* __restrict__ pos) {
    const int t = threadIdx.x;
    const int lane = t & 63;
    const int i = blockIdx.x * 4 + (t >> 6);
    const float* pa = zi + (size_t)i * D_DIM + lane * 8;
    const float* pb = zj + (size_t)i * D_DIM + lane * 8;
    const float4 a0 = *(const float4*)pa;
    const float4 a1 = *(const float4*)(pa + 4);
    const float4 b0 = *(const float4*)pb;
    const float4 b1 = *(const float4*)(pb + 4);
    float ssi = a0.x*a0.x + a0.y*a0.y + a0.z*a0.z + a0.w*a0.w
              + a1.x*a1.x + a1.y*a1.y + a1.z*a1.z + a1.w*a1.w;
    float ssj = b0.x*b0.x + b0.y*b0.y + b0.z*b0.z + b0.w*b0.w
              + b1.x*b1.x + b1.y*b1.y + b1.z*b1.z + b1.w*b1.w;
    float dt  = a0.x*b0.x + a0.y*b0.y + a0.z*b0.z + a0.w*b0.w
              + a1.x*b1.x + a1.y*b1.y + a1.z*b1.z + a1.w*b1.w;
    #pragma unroll
    for (int off = 1; off < 64; off <<= 1) {
        ssi += __shfl_xor(ssi, off);
        ssj += __shfl_xor(ssj, off);
        dt  += __shfl_xor(dt,  off);
    }
    const float si = 1.0f / fmaxf(sqrtf(ssi), 1e-12f);
    const float sj = 1.0f / fmaxf(sqrtf(ssj), 1e-12f);
    // pack 8 normalized values (k = lane*8 .. +8) -> 8 fp8 e4m3 (HW RNE)
    uint2 pi8, pj8;
    {
        int w0 = 0, w1 = 0;
        w0 = __builtin_amdgcn_cvt_pk_fp8_f32(a0.x * si, a0.y * si, w0, false);
        w0 = __builtin_amdgcn_cvt_pk_fp8_f32(a0.z * si, a0.w * si, w0, true);
        w1 = __builtin_amdgcn_cvt_pk_fp8_f32(a1.x * si, a1.y * si, w1, false);
        w1 = __builtin_amdgcn_cvt_pk_fp8_f32(a1.z * si, a1.w * si, w1, true);
        pi8.x = (unsigned)w0; pi8.y = (unsigned)w1;
        w0 = 0; w1 = 0;
        w0 = __builtin_amdgcn_cvt_pk_fp8_f32(b0.x * sj, b0.y * sj, w0, false);
        w0 = __builtin_amdgcn_cvt_pk_fp8_f32(b0.z * sj, b0.w * sj, w0, true);
        w1 = __builtin_amdgcn_cvt_pk_fp8_f32(b1.x * sj, b1.y * sj, w1, false);
        w1 = __builtin_amdgcn_cvt_pk_fp8_f32(b1.z * sj, b1.w * sj, w1, true);
        pj8.x = (unsigned)w0; pj8.y = (unsigned)w1;
    }
    // lane's k-octet o = lane&7 within hp = lane>>3; byte slot = (o&3)*16 + (o>>2)*8
    const size_t PLANE = (size_t)N_ROWS * 64;  // bytes per hp-plane
    const int o = lane & 7;
    const size_t off0 = (size_t)(lane >> 3) * PLANE + (o & 3) * 16 + (o >> 2) * 8;
    *(uint2*)(Zn + off0 + (size_t)i * 64) = pi8;
    *(uint2*)(Zn + off0 + (size_t)(B_ROWS + i) * 64) = pj8;
    if (lane == 0) pos[i] = 20.0f * dt * si * sj;  // positive logit counted twice: 2*dot/T
}

// ---------------- K2: symmetric fused S = Zn·Zn^T (fp8 MFMA) + per-row sum(exp(S/T)) ------
// ONE WAVE per block, 64x64 tile pair. NO LDS, no barriers, 4 waves/SIMD (VGPR 128 incl acc).
// CU-compact ordering: within an off-diag super-pair, slot s = q*32+r maps to
// di = r&15, dj = (r>>4)*8 + q. A CU's resident blocks have FIXED r (alignment above)
// -> they all share ONE A panel (L1-hot, ~8-16x reuse) and sweep 8 B panels (L2-hot).
__global__ __launch_bounds__(64, 4) void k_gemm_lse(const unsigned char* __restrict__ Zn,
                                                    float* __restrict__ rowsum_g) {
    const int lane = threadIdx.x & 63;
    const int l15  = lane & 15, lhi = lane >> 4;

    // XCD-aware swizzle (bijective: NBLK % 8 == 0)
    const int s = (blockIdx.x & 7) * (NBLK / 8) + (blockIdx.x >> 3);
    int SI, SJ, di, dj;
    if (s < NOFF) {
        const int sp = s >> 8;       // off-diag super-pair 0..27
        int g = s & 255;
        int a = 0, b = 1;
        for (int k = 0; k < sp; ++k) { if (++b == 8) { ++a; b = a + 1; } }
        SI = a; SJ = b;
        const int q = g >> 5, r = g & 31;
        di = r & 15; dj = (r >> 4) * 8 + q;
    } else {
        int g = s - NOFF;
        const int S = g / 160;
        g = g % 160;
        if (g >= 136) return;        // padding slot
        SI = SJ = S;
        di = 0;
        while (g >= 16 - di) { g -= 16 - di; ++di; }
        dj = di + g;
    }
    const int I = SI * 16 + di, J = SJ * 16 + dj;
    const bool dg = (I == J);
    const int rowB = I * 64;               // wave's first output row
    const int colB = J * 64;               // wave's first output col

    const char* Zb = (const char*)Zn;
    const size_t PLANE = (size_t)N_ROWS * 64;  // bytes per hp-plane

    // fragment base pointers: lane (lhi,l15) reads row (base + l15 + 16*frag), slot lhi
    const char* pA = Zb + ((size_t)(rowB + l15)) * 64 + lhi * 16;
    const char* pB = Zb + ((size_t)(colB + l15)) * 64 + lhi * 16;

    f32x4 acc[4][4];
    #pragma unroll
    for (int a = 0; a < 4; ++a)
        #pragma unroll
        for (int b = 0; b < 4; ++b)
            #pragma unroll
            for (int q = 0; q < 4; ++q) acc[a][b][q] = 0.0f;

    for (int hp = 0; hp < NHP; ++hp) {
        f8x16 af[4], bg[4];
        const char* _a = pA + (size_t)hp * PLANE;
        const char* _b = pB + (size_t)hp * PLANE;
        #pragma unroll
        for (int mi = 0; mi < 4; ++mi) af[mi] = *(const f8x16*)(_a + mi * 1024);
        #pragma unroll
        for (int ni = 0; ni < 4; ++ni) bg[ni] = *(const f8x16*)(_b + ni * 1024);
        __builtin_amdgcn_s_setprio(1);
        #pragma unroll
        for (int mi = 0; mi < 4; ++mi)
            #pragma unroll
            for (int ni = 0; ni < 4; ++ni)
                acc[mi][ni] = __builtin_amdgcn_mfma_f32_16x16x32_fp8_fp8(
                    af[mi][0], bg[ni][0], acc[mi][ni], 0, 0, 0);
        #pragma unroll
        for (int mi = 0; mi < 4; ++mi)
            #pragma unroll
            for (int ni = 0; ni < 4; ++ni)
                acc[mi][ni] = __builtin_amdgcn_mfma_f32_16x16x32_fp8_fp8(
                    af[mi][1], bg[ni][1], acc[mi][ni], 0, 0, 0);
        __builtin_amdgcn_s_setprio(0);
    }

    // epilogue: e = exp2(S * 10*log2e); C/D layout: col=lane&15, row=(lane>>4)*4+reg
    float colsum[4] = {0.0f, 0.0f, 0.0f, 0.0f};
    #pragma unroll
    for (int mi = 0; mi < 4; ++mi) {
        const int growb = rowB + mi * 16 + lhi * 4;
        float rs[4] = {0.0f, 0.0f, 0.0f, 0.0f};
        if (dg) {
            #pragma unroll
            for (int ni = 0; ni < 4; ++ni) {
                const int gcol = colB + ni * 16 + l15;
                #pragma unroll
                for (int r = 0; r < 4; ++r) {
                    float arg = acc[mi][ni][r] * SCALE_L2E;
                    if (growb + r == gcol) arg = -1e30f;  // diagonal mask -> exp2 = 0
                    rs[r] += exp2f(arg);
                }
            }
        } else {
            #pragma unroll
            for (int ni = 0; ni < 4; ++ni)
                #pragma unroll
                for (int r = 0; r < 4; ++r) {
                    const float e = exp2f(acc[mi][ni][r] * SCALE_L2E);
                    rs[r] += e;
                    colsum[ni] += e;
                }
        }
        // row sums: reduce the 16 lanes sharing lhi; one atomic per (mi, r)
        #pragma unroll
        for (int r = 0; r < 4; ++r) {
            float v = rs[r];
            v += __shfl_xor(v, 1);
            v += __shfl_xor(v, 2);
            v += __shfl_xor(v, 4);
            v += __shfl_xor(v, 8);
            if (l15 == 0) atomicAdd(&rowsum_g[growb + r], v);
        }
    }
    if (!dg) {
        // column sums (symmetry): reduce across lhi groups; lanes lhi==0 hold col l15
        #pragma unroll
        for (int ni = 0; ni < 4; ++ni) {
            float c = colsum[ni];
            c += __shfl_xor(c, 16);
            c += __shfl_xor(c, 32);
            if (lhi == 0)
                atomicAdd(&rowsum_g[colB + ni * 16 + l15], c);
        }
    }
}

// ---------------- K3: loss = mean(ln(rowsum)) - mean(pos), single block ----------------
__global__ __launch_bounds__(1024) void k_finalize(const float* __restrict__ rowsum_g,
                                                   const float* __restrict__ pos,
                                                   float* __restrict__ out) {
    const int t = threadIdx.x;
    float l = 0.0f, p = 0.0f;
    #pragma unroll
    for (int q = 0; q < N_ROWS / 1024; ++q) l += logf(rowsum_g[t + q * 1024]);
    #pragma unroll
    for (int q = 0; q < B_ROWS / 1024; ++q) p += pos[t + q * 1024];
    #pragma unroll
    for (int off = 1; off < 64; off <<= 1) {
        l += __shfl_xor(l, off);
        p += __shfl_xor(p, off);
    }
    __shared__ float red[2][16];
    if ((t & 63) == 0) { red[0][t >> 6] = l; red[1][t >> 6] = p; }
    __syncthreads();
    if (t == 0) {
        float L = 0.0f, P = 0.0f;
        #pragma unroll
        for (int q = 0; q < 16; ++q) { L += red[0][q]; P += red[1][q]; }
        out[0] = (L - P) * (1.0f / (float)N_ROWS);
    }
}

extern "C" void kernel_launch(void* const* d_in, const int* in_sizes, int n_in,
                              void* d_out, int out_size, void* d_ws, size_t ws_size,
                              hipStream_t stream) {
    (void)in_sizes; (void)n_in; (void)out_size; (void)ws_size;
    const float* zi = (const float*)d_in[0];
    const float* zj = (const float*)d_in[1];

    // workspace layout
    const size_t ZN_BYTES = (size_t)N_ROWS * D_DIM;  // 4 MiB fp8 (hp-tiled)
    unsigned char* Zn     = (unsigned char*)d_ws;
    float* rowsum_g       = (float*)((char*)d_ws + ZN_BYTES);              // 8192 f32
    float* pos            = (float*)((char*)d_ws + ZN_BYTES + N_ROWS * 4); // 4096 f32

    // zero the atomically-accumulated rowsums
    hipMemsetAsync(rowsum_g, 0, N_ROWS * 4, stream);

    k_normalize<<<B_ROWS / 4, 256, 0, stream>>>(zi, zj, Zn, pos);
    k_gemm_lse<<<NBLK, 64, 0, stream>>>(Zn, rowsum_g);
    k_finalize<<<1, 1024, 0, stream>>>(rowsum_g, pos, (float*)d_out);
}

// Round 15
// 57.585 us; speedup vs baseline: 3.2249x; 1.0551x over previous
//
#include <hip/hip_runtime.h>
#include <stdint.h>

// Problem constants
#define D_DIM 512
#define B_ROWS 4096
#define N_ROWS 8192
// (1/TEMPERATURE) * log2(e) : exp(x/T) == exp2(x * SCALE_L2E)
#define SCALE_L2E 14.426950408889634f

#define NHP 8                       // K-blocks of 64 (each = two K=32 MFMA steps)
// 64-row tiles: 128. Supers of 16 tiles (8 supers of 1024 rows).
// Off-diag super-pairs (SI<SJ): 28, 256 blocks each, first (7168 slots, 256-aligned).
// Diag supers: 8, padded to 160 slots each (136 used), appended (starts 32-aligned).
// NBLK = 7168 + 1280 = 8448 = 8 * 1056; 1056 % 32 == 0 -> every XCD chunk and super
// start is 32-aligned, so each CU sees a FIXED r = s%32 within any off-diag super.
#define NOFF (28 * 256)
#define NBLK (NOFF + 8 * 160)

typedef __attribute__((ext_vector_type(4))) float f32x4;
typedef __attribute__((ext_vector_type(2))) long f8x16;  // 16 fp8 bytes = dwordx4

// ---------------- K1: normalize rows -> fp8 e4m3 Zn (hp-interleaved), fp32 pos -------------
// Zn layout: [hp=0..7][row=0..8191][64 B]; byte slot lhi*16 holds k-octet (64hp+lhi*8..+8)
// and slot lhi*16+8 holds (64hp+32+lhi*8..+8) => one dwordx4 fragment load provides the
// MFMA A/B operands for BOTH K=32 steps of the hp.
__global__ __launch_bounds__(256) void k_normalize(const float* __restrict__ zi,
                                                   const float* __restrict__ zj,
                                                   unsigned char* __restrict__ Zn,
                                                   float* __restrict__ pos) {
    const int t = threadIdx.x;
    const int lane = t & 63;
    const int i = blockIdx.x * 4 + (t >> 6);
    const float* pa = zi + (size_t)i * D_DIM + lane * 8;
    const float* pb = zj + (size_t)i * D_DIM + lane * 8;
    const float4 a0 = *(const float4*)pa;
    const float4 a1 = *(const float4*)(pa + 4);
    const float4 b0 = *(const float4*)pb;
    const float4 b1 = *(const float4*)(pb + 4);
    float ssi = a0.x*a0.x + a0.y*a0.y + a0.z*a0.z + a0.w*a0.w
              + a1.x*a1.x + a1.y*a1.y + a1.z*a1.z + a1.w*a1.w;
    float ssj = b0.x*b0.x + b0.y*b0.y + b0.z*b0.z + b0.w*b0.w
              + b1.x*b1.x + b1.y*b1.y + b1.z*b1.z + b1.w*b1.w;
    float dt  = a0.x*b0.x + a0.y*b0.y + a0.z*b0.z + a0.w*b0.w
              + a1.x*b1.x + a1.y*b1.y + a1.z*b1.z + a1.w*b1.w;
    #pragma unroll
    for (int off = 1; off < 64; off <<= 1) {
        ssi += __shfl_xor(ssi, off);
        ssj += __shfl_xor(ssj, off);
        dt  += __shfl_xor(dt,  off);
    }
    const float si = 1.0f / fmaxf(sqrtf(ssi), 1e-12f);
    const float sj = 1.0f / fmaxf(sqrtf(ssj), 1e-12f);
    // pack 8 normalized values (k = lane*8 .. +8) -> 8 fp8 e4m3 (HW RNE)
    uint2 pi8, pj8;
    {
        int w0 = 0, w1 = 0;
        w0 = __builtin_amdgcn_cvt_pk_fp8_f32(a0.x * si, a0.y * si, w0, false);
        w0 = __builtin_amdgcn_cvt_pk_fp8_f32(a0.z * si, a0.w * si, w0, true);
        w1 = __builtin_amdgcn_cvt_pk_fp8_f32(a1.x * si, a1.y * si, w1, false);
        w1 = __builtin_amdgcn_cvt_pk_fp8_f32(a1.z * si, a1.w * si, w1, true);
        pi8.x = (unsigned)w0; pi8.y = (unsigned)w1;
        w0 = 0; w1 = 0;
        w0 = __builtin_amdgcn_cvt_pk_fp8_f32(b0.x * sj, b0.y * sj, w0, false);
        w0 = __builtin_amdgcn_cvt_pk_fp8_f32(b0.z * sj, b0.w * sj, w0, true);
        w1 = __builtin_amdgcn_cvt_pk_fp8_f32(b1.x * sj, b1.y * sj, w1, false);
        w1 = __builtin_amdgcn_cvt_pk_fp8_f32(b1.z * sj, b1.w * sj, w1, true);
        pj8.x = (unsigned)w0; pj8.y = (unsigned)w1;
    }
    // lane's k-octet o = lane&7 within hp = lane>>3; byte slot = (o&3)*16 + (o>>2)*8
    const size_t PLANE = (size_t)N_ROWS * 64;  // bytes per hp-plane
    const int o = lane & 7;
    const size_t off0 = (size_t)(lane >> 3) * PLANE + (o & 3) * 16 + (o >> 2) * 8;
    *(uint2*)(Zn + off0 + (size_t)i * 64) = pi8;
    *(uint2*)(Zn + off0 + (size_t)(B_ROWS + i) * 64) = pj8;
    if (lane == 0) pos[i] = 20.0f * dt * si * sj;  // positive logit counted twice: 2*dot/T
}

// ---------------- K2: symmetric fused S = Zn·Zn^T (fp8 MFMA) + per-row sum(exp(S/T)) ------
// ONE WAVE per block, 64x64 tile pair. NO LDS, no barriers. CU-compact ordering (r14).
// NEW: 2-deep register double-buffer across hp -- issue hp+1's 8 loads BEFORE hp's MFMA
// burst, so the VMEM queue time overlaps the 620cy matrix burst instead of serializing.
// Explicit even/odd buffers, unrolled x2, all static indexing (rule-20-safe).
// VGPR ~ acc 64 + frags 2x32 + addr ~= 140 -> 3 waves/SIMD.
__global__ __launch_bounds__(64, 3) void k_gemm_lse(const unsigned char* __restrict__ Zn,
                                                    float* __restrict__ rowsum_g) {
    const int lane = threadIdx.x & 63;
    const int l15  = lane & 15, lhi = lane >> 4;

    // XCD-aware swizzle (bijective: NBLK % 8 == 0)
    const int s = (blockIdx.x & 7) * (NBLK / 8) + (blockIdx.x >> 3);
    int SI, SJ, di, dj;
    if (s < NOFF) {
        const int sp = s >> 8;       // off-diag super-pair 0..27
        int g = s & 255;
        int a = 0, b = 1;
        for (int k = 0; k < sp; ++k) { if (++b == 8) { ++a; b = a + 1; } }
        SI = a; SJ = b;
        const int q = g >> 5, r = g & 31;
        di = r & 15; dj = (r >> 4) * 8 + q;
    } else {
        int g = s - NOFF;
        const int S = g / 160;
        g = g % 160;
        if (g >= 136) return;        // padding slot
        SI = SJ = S;
        di = 0;
        while (g >= 16 - di) { g -= 16 - di; ++di; }
        dj = di + g;
    }
    const int I = SI * 16 + di, J = SJ * 16 + dj;
    const bool dg = (I == J);
    const int rowB = I * 64;               // wave's first output row
    const int colB = J * 64;               // wave's first output col

    const char* Zb = (const char*)Zn;
    const size_t PLANE = (size_t)N_ROWS * 64;  // bytes per hp-plane

    // fragment base pointers: lane (lhi,l15) reads row (base + l15 + 16*frag), slot lhi
    const char* pA = Zb + ((size_t)(rowB + l15)) * 64 + lhi * 16;
    const char* pB = Zb + ((size_t)(colB + l15)) * 64 + lhi * 16;

    f8x16 af0[4], bg0[4], af1[4], bg1[4];

#define LOADAB(dstA, dstB, hp)                                                      \
    do {                                                                            \
        const char* _a = pA + (size_t)(hp) * PLANE;                                 \
        const char* _b = pB + (size_t)(hp) * PLANE;                                 \
        _Pragma("unroll")                                                           \
        for (int mi = 0; mi < 4; ++mi) dstA[mi] = *(const f8x16*)(_a + mi * 1024);  \
        _Pragma("unroll")                                                           \
        for (int ni = 0; ni < 4; ++ni) dstB[ni] = *(const f8x16*)(_b + ni * 1024);  \
    } while (0)

#define MFMAAB(srcA, srcB)                                                          \
    do {                                                                            \
        __builtin_amdgcn_s_setprio(1);                                              \
        _Pragma("unroll")                                                           \
        for (int mi = 0; mi < 4; ++mi)                                              \
            _Pragma("unroll")                                                       \
            for (int ni = 0; ni < 4; ++ni)                                          \
                acc[mi][ni] = __builtin_amdgcn_mfma_f32_16x16x32_fp8_fp8(           \
                    srcA[mi][0], srcB[ni][0], acc[mi][ni], 0, 0, 0);                \
        _Pragma("unroll")                                                           \
        for (int mi = 0; mi < 4; ++mi)                                              \
            _Pragma("unroll")                                                       \
            for (int ni = 0; ni < 4; ++ni)                                          \
                acc[mi][ni] = __builtin_amdgcn_mfma_f32_16x16x32_fp8_fp8(           \
                    srcA[mi][1], srcB[ni][1], acc[mi][ni], 0, 0, 0);                \
        __builtin_amdgcn_s_setprio(0);                                              \
    } while (0)

    f32x4 acc[4][4];
    #pragma unroll
    for (int a = 0; a < 4; ++a)
        #pragma unroll
        for (int b = 0; b < 4; ++b)
            #pragma unroll
            for (int q = 0; q < 4; ++q) acc[a][b][q] = 0.0f;

    // software pipeline: loads for hp+1 issue before the MFMA burst of hp
    LOADAB(af0, bg0, 0);
    #pragma unroll
    for (int hp = 0; hp < NHP; hp += 2) {
        if (hp + 1 < NHP) LOADAB(af1, bg1, hp + 1);
        MFMAAB(af0, bg0);
        if (hp + 2 < NHP) LOADAB(af0, bg0, hp + 2);
        if (hp + 1 < NHP) MFMAAB(af1, bg1);
    }

    // epilogue: e = exp2(S * 10*log2e); C/D layout: col=lane&15, row=(lane>>4)*4+reg
    float colsum[4] = {0.0f, 0.0f, 0.0f, 0.0f};
    #pragma unroll
    for (int mi = 0; mi < 4; ++mi) {
        const int growb = rowB + mi * 16 + lhi * 4;
        float rs[4] = {0.0f, 0.0f, 0.0f, 0.0f};
        if (dg) {
            #pragma unroll
            for (int ni = 0; ni < 4; ++ni) {
                const int gcol = colB + ni * 16 + l15;
                #pragma unroll
                for (int r = 0; r < 4; ++r) {
                    float arg = acc[mi][ni][r] * SCALE_L2E;
                    if (growb + r == gcol) arg = -1e30f;  // diagonal mask -> exp2 = 0
                    rs[r] += exp2f(arg);
                }
            }
        } else {
            #pragma unroll
            for (int ni = 0; ni < 4; ++ni)
                #pragma unroll
                for (int r = 0; r < 4; ++r) {
                    const float e = exp2f(acc[mi][ni][r] * SCALE_L2E);
                    rs[r] += e;
                    colsum[ni] += e;
                }
        }
        // row sums: reduce the 16 lanes sharing lhi; one atomic per (mi, r)
        #pragma unroll
        for (int r = 0; r < 4; ++r) {
            float v = rs[r];
            v += __shfl_xor(v, 1);
            v += __shfl_xor(v, 2);
            v += __shfl_xor(v, 4);
            v += __shfl_xor(v, 8);
            if (l15 == 0) atomicAdd(&rowsum_g[growb + r], v);
        }
    }
    if (!dg) {
        // column sums (symmetry): reduce across lhi groups; lanes lhi==0 hold col l15
        #pragma unroll
        for (int ni = 0; ni < 4; ++ni) {
            float c = colsum[ni];
            c += __shfl_xor(c, 16);
            c += __shfl_xor(c, 32);
            if (lhi == 0)
                atomicAdd(&rowsum_g[colB + ni * 16 + l15], c);
        }
    }
#undef LOADAB
#undef MFMAAB
}

// ---------------- K3: loss = mean(ln(rowsum)) - mean(pos), single block ----------------
__global__ __launch_bounds__(1024) void k_finalize(const float* __restrict__ rowsum_g,
                                                   const float* __restrict__ pos,
                                                   float* __restrict__ out) {
    const int t = threadIdx.x;
    float l = 0.0f, p = 0.0f;
    #pragma unroll
    for (int q = 0; q < N_ROWS / 1024; ++q) l += logf(rowsum_g[t + q * 1024]);
    #pragma unroll
    for (int q = 0; q < B_ROWS / 1024; ++q) p += pos[t + q * 1024];
    #pragma unroll
    for (int off = 1; off < 64; off <<= 1) {
        l += __shfl_xor(l, off);
        p += __shfl_xor(p, off);
    }
    __shared__ float red[2][16];
    if ((t & 63) == 0) { red[0][t >> 6] = l; red[1][t >> 6] = p; }
    __syncthreads();
    if (t == 0) {
        float L = 0.0f, P = 0.0f;
        #pragma unroll
        for (int q = 0; q < 16; ++q) { L += red[0][q]; P += red[1][q]; }
        out[0] = (L - P) * (1.0f / (float)N_ROWS);
    }
}

extern "C" void kernel_launch(void* const* d_in, const int* in_sizes, int n_in,
                              void* d_out, int out_size, void* d_ws, size_t ws_size,
                              hipStream_t stream) {
    (void)in_sizes; (void)n_in; (void)out_size; (void)ws_size;
    const float* zi = (const float*)d_in[0];
    const float* zj = (const float*)d_in[1];

    // workspace layout
    const size_t ZN_BYTES = (size_t)N_ROWS * D_DIM;  // 4 MiB fp8 (hp-tiled)
    unsigned char* Zn     = (unsigned char*)d_ws;
    float* rowsum_g       = (float*)((char*)d_ws + ZN_BYTES);              // 8192 f32
    float* pos            = (float*)((char*)d_ws + ZN_BYTES + N_ROWS * 4); // 4096 f32

    // zero the atomically-accumulated rowsums
    hipMemsetAsync(rowsum_g, 0, N_ROWS * 4, stream);

    k_normalize<<<B_ROWS / 4, 256, 0, stream>>>(zi, zj, Zn, pos);
    k_gemm_lse<<<NBLK, 64, 0, stream>>>(Zn, rowsum_g);
    k_finalize<<<1, 1024, 0, stream>>>(rowsum_g, pos, (float*)d_out);
}

// Round 16
// 56.092 us; speedup vs baseline: 3.3107x; 1.0266x over previous
//
#include <hip/hip_runtime.h>
#include <stdint.h>

// Problem constants
#define D_DIM 512
#define B_ROWS 4096
#define N_ROWS 8192
// (1/TEMPERATURE) * log2(e) : exp(x/T) == exp2(x * SCALE_L2E)
#define SCALE_L2E 14.426950408889634f

#define NHP 8                       // K-blocks of 64 (each = two K=32 MFMA steps)
// 128x128 cells (a<=b over 64 cells/side): 2080. Each cell = 2 blocks of 64 rows x 128
// cols. Supertiled: supers of 8 cells; 28 off-diag SPs x 64 cells + 8 diag SPs x 36 cells.
// NBLK = 28*128 + 8*72 = 4160 = 8 * 520 (bijective XCD swizzle).
#define NOFFS (28 * 128)
#define NBLK (NOFFS + 8 * 72)
// per-ni-half write modes
#define WM_NONE 0
#define WM_DIAG 1
#define WM_FULL 2

typedef __attribute__((ext_vector_type(4))) float f32x4;
typedef __attribute__((ext_vector_type(2))) long f8x16;  // 16 fp8 bytes = dwordx4

// ---------------- K1: normalize rows -> fp8 e4m3 Zn (hp-interleaved), fp32 pos;
//                     also zeros the rowsum accumulator (blocks 0..7) -------------
// Zn layout: [hp=0..7][row=0..8191][64 B]; byte slot lhi*16 holds k-octet (64hp+lhi*8..+8),
// slot lhi*16+8 holds (64hp+32+lhi*8..+8) => one dwordx4 fragment load provides the MFMA
// operands for BOTH K=32 steps of the hp.
__global__ __launch_bounds__(256) void k_normalize(const float* __restrict__ zi,
                                                   const float* __restrict__ zj,
                                                   unsigned char* __restrict__ Zn,
                                                   float* __restrict__ pos,
                                                   float* __restrict__ rowsum_g) {
    const int t = threadIdx.x;
    if (blockIdx.x < 8) {  // zero rowsum (runs before k_gemm in-stream; no race)
        float4 z = {0.0f, 0.0f, 0.0f, 0.0f};
        *(float4*)(rowsum_g + blockIdx.x * 1024 + t * 4) = z;
    }
    const int lane = t & 63;
    const int i = blockIdx.x * 4 + (t >> 6);
    const float* pa = zi + (size_t)i * D_DIM + lane * 8;
    const float* pb = zj + (size_t)i * D_DIM + lane * 8;
    const float4 a0 = *(const float4*)pa;
    const float4 a1 = *(const float4*)(pa + 4);
    const float4 b0 = *(const float4*)pb;
    const float4 b1 = *(const float4*)(pb + 4);
    float ssi = a0.x*a0.x + a0.y*a0.y + a0.z*a0.z + a0.w*a0.w
              + a1.x*a1.x + a1.y*a1.y + a1.z*a1.z + a1.w*a1.w;
    float ssj = b0.x*b0.x + b0.y*b0.y + b0.z*b0.z + b0.w*b0.w
              + b1.x*b1.x + b1.y*b1.y + b1.z*b1.z + b1.w*b1.w;
    float dt  = a0.x*b0.x + a0.y*b0.y + a0.z*b0.z + a0.w*b0.w
              + a1.x*b1.x + a1.y*b1.y + a1.z*b1.z + a1.w*b1.w;
    #pragma unroll
    for (int off = 1; off < 64; off <<= 1) {
        ssi += __shfl_xor(ssi, off);
        ssj += __shfl_xor(ssj, off);
        dt  += __shfl_xor(dt,  off);
    }
    const float si = 1.0f / fmaxf(sqrtf(ssi), 1e-12f);
    const float sj = 1.0f / fmaxf(sqrtf(ssj), 1e-12f);
    uint2 pi8, pj8;
    {
        int w0 = 0, w1 = 0;
        w0 = __builtin_amdgcn_cvt_pk_fp8_f32(a0.x * si, a0.y * si, w0, false);
        w0 = __builtin_amdgcn_cvt_pk_fp8_f32(a0.z * si, a0.w * si, w0, true);
        w1 = __builtin_amdgcn_cvt_pk_fp8_f32(a1.x * si, a1.y * si, w1, false);
        w1 = __builtin_amdgcn_cvt_pk_fp8_f32(a1.z * si, a1.w * si, w1, true);
        pi8.x = (unsigned)w0; pi8.y = (unsigned)w1;
        w0 = 0; w1 = 0;
        w0 = __builtin_amdgcn_cvt_pk_fp8_f32(b0.x * sj, b0.y * sj, w0, false);
        w0 = __builtin_amdgcn_cvt_pk_fp8_f32(b0.z * sj, b0.w * sj, w0, true);
        w1 = __builtin_amdgcn_cvt_pk_fp8_f32(b1.x * sj, b1.y * sj, w1, false);
        w1 = __builtin_amdgcn_cvt_pk_fp8_f32(b1.z * sj, b1.w * sj, w1, true);
        pj8.x = (unsigned)w0; pj8.y = (unsigned)w1;
    }
    const size_t PLANE = (size_t)N_ROWS * 64;  // bytes per hp-plane
    const int o = lane & 7;
    const size_t off0 = (size_t)(lane >> 3) * PLANE + (o & 3) * 16 + (o >> 2) * 8;
    *(uint2*)(Zn + off0 + (size_t)i * 64) = pi8;
    *(uint2*)(Zn + off0 + (size_t)(B_ROWS + i) * 64) = pj8;
    if (lane == 0) pos[i] = 20.0f * dt * si * sj;  // positive logit counted twice: 2*dot/T
}

// ---------------- K2: symmetric fused S = Zn·Zn^T (fp8 MFMA) + per-row sum(exp(S/T)) ------
// ONE WAVE per block, 64x128 output tile (acc 4x8, 128 AGPR). NO LDS, no barriers.
// 2-deep register double-buffer: hp+1's 12 loads issue before hp's 64-MFMA burst.
// Cell (a,b) (128x128, a<=b) = 2 half-blocks (rows 2a / 2a+1). Write flags per ni-half:
// off-diag cell: FULL/FULL both halves. Diag cell half0: DIAG (masked rows only) + FULL;
// half1: NONE (duplicate of half0's (0,1) quadrant) + DIAG. Compute is always full.
__global__ __launch_bounds__(64, 2) void k_gemm_lse(const unsigned char* __restrict__ Zn,
                                                    float* __restrict__ rowsum_g) {
    const int lane = threadIdx.x & 63;
    const int l15  = lane & 15, lhi = lane >> 4;

    // XCD-aware swizzle (bijective: NBLK % 8 == 0), then supertiled cell decode
    const int s = (blockIdx.x & 7) * (NBLK / 8) + (blockIdx.x >> 3);
    int a, b, half;
    if (s < NOFFS) {
        const int sp = s >> 7;          // off-diag super-pair 0..27
        const int u  = s & 127;
        int A0 = 0, B0 = 1;
        for (int k = 0; k < sp; ++k) { if (++B0 == 8) { ++A0; B0 = A0 + 1; } }
        const int cell = u >> 1;
        a = A0 * 8 + (cell >> 3);
        b = B0 * 8 + (cell & 7);
        half = u & 1;
    } else {
        int v = s - NOFFS;
        const int S = v / 72; v %= 72;
        const int c = v >> 1;           // 0..35 over (di<=dj) in 8x8
        half = v & 1;
        int di = 0, g = c;
        while (g >= 8 - di) { g -= 8 - di; ++di; }
        a = S * 8 + di;
        b = S * 8 + di + g;
    }
    const bool dgcell = (a == b);
    // write modes for ni-halves (cols [2b*64,+64) and [2b*64+64,+64))
    int m0 = WM_FULL, m1 = WM_FULL;
    if (dgcell) {
        if (half == 0) { m0 = WM_DIAG; m1 = WM_FULL; }
        else           { m0 = WM_NONE; m1 = WM_DIAG; }
    }
    const int rowB = (2 * a + half) * 64;   // wave's 64 output rows
    const int colB = 2 * b * 64;            // wave's 128 output cols

    const char* Zb = (const char*)Zn;
    const size_t PLANE = (size_t)N_ROWS * 64;  // bytes per hp-plane

    const char* pA = Zb + ((size_t)(rowB + l15)) * 64 + lhi * 16;
    const char* pB = Zb + ((size_t)(colB + l15)) * 64 + lhi * 16;

    f8x16 af0[4], af1[4], bg0[8], bg1[8];

#define LOADAB(dstA, dstB, hp)                                                      \
    do {                                                                            \
        const char* _a = pA + (size_t)(hp) * PLANE;                                 \
        const char* _b = pB + (size_t)(hp) * PLANE;                                 \
        _Pragma("unroll")                                                           \
        for (int mi = 0; mi < 4; ++mi) dstA[mi] = *(const f8x16*)(_a + mi * 1024);  \
        _Pragma("unroll")                                                           \
        for (int ni = 0; ni < 8; ++ni) dstB[ni] = *(const f8x16*)(_b + ni * 1024);  \
    } while (0)

#define MFMAAB(srcA, srcB)                                                          \
    do {                                                                            \
        __builtin_amdgcn_s_setprio(1);                                              \
        _Pragma("unroll")                                                           \
        for (int mi = 0; mi < 4; ++mi)                                              \
            _Pragma("unroll")                                                       \
            for (int ni = 0; ni < 8; ++ni)                                          \
                acc[mi][ni] = __builtin_amdgcn_mfma_f32_16x16x32_fp8_fp8(           \
                    srcA[mi][0], srcB[ni][0], acc[mi][ni], 0, 0, 0);                \
        _Pragma("unroll")                                                           \
        for (int mi = 0; mi < 4; ++mi)                                              \
            _Pragma("unroll")                                                       \
            for (int ni = 0; ni < 8; ++ni)                                          \
                acc[mi][ni] = __builtin_amdgcn_mfma_f32_16x16x32_fp8_fp8(           \
                    srcA[mi][1], srcB[ni][1], acc[mi][ni], 0, 0, 0);                \
        __builtin_amdgcn_s_setprio(0);                                              \
    } while (0)

    f32x4 acc[4][8];
    #pragma unroll
    for (int x = 0; x < 4; ++x)
        #pragma unroll
        for (int y = 0; y < 8; ++y)
            #pragma unroll
            for (int q = 0; q < 4; ++q) acc[x][y][q] = 0.0f;

    // software pipeline: loads for hp+1 issue before the MFMA burst of hp
    LOADAB(af0, bg0, 0);
    #pragma unroll
    for (int hp = 0; hp < NHP; hp += 2) {
        if (hp + 1 < NHP) LOADAB(af1, bg1, hp + 1);
        MFMAAB(af0, bg0);
        if (hp + 2 < NHP) LOADAB(af0, bg0, hp + 2);
        if (hp + 1 < NHP) MFMAAB(af1, bg1);
    }

    // epilogue: e = exp2(S * 10*log2e); C/D layout: col=lane&15, row=(lane>>4)*4+reg
    float colsum[8] = {0.0f, 0.0f, 0.0f, 0.0f, 0.0f, 0.0f, 0.0f, 0.0f};
    #pragma unroll
    for (int mi = 0; mi < 4; ++mi) {
        const int growb = rowB + mi * 16 + lhi * 4;
        float rs[4] = {0.0f, 0.0f, 0.0f, 0.0f};
        // ni-half 0 (cols colB .. colB+63)
        if (m0 == WM_FULL) {
            #pragma unroll
            for (int ni = 0; ni < 4; ++ni)
                #pragma unroll
                for (int r = 0; r < 4; ++r) {
                    const float e = exp2f(acc[mi][ni][r] * SCALE_L2E);
                    rs[r] += e;
                    colsum[ni] += e;
                }
        } else if (m0 == WM_DIAG) {
            #pragma unroll
            for (int ni = 0; ni < 4; ++ni) {
                const int gcol = colB + ni * 16 + l15;
                #pragma unroll
                for (int r = 0; r < 4; ++r) {
                    float arg = acc[mi][ni][r] * SCALE_L2E;
                    if (growb + r == gcol) arg = -1e30f;  // diagonal mask -> exp2 = 0
                    rs[r] += exp2f(arg);
                }
            }
        }
        // ni-half 1 (cols colB+64 .. colB+127)
        if (m1 == WM_FULL) {
            #pragma unroll
            for (int ni = 4; ni < 8; ++ni)
                #pragma unroll
                for (int r = 0; r < 4; ++r) {
                    const float e = exp2f(acc[mi][ni][r] * SCALE_L2E);
                    rs[r] += e;
                    colsum[ni] += e;
                }
        } else {  // WM_DIAG
            #pragma unroll
            for (int ni = 4; ni < 8; ++ni) {
                const int gcol = colB + ni * 16 + l15;
                #pragma unroll
                for (int r = 0; r < 4; ++r) {
                    float arg = acc[mi][ni][r] * SCALE_L2E;
                    if (growb + r == gcol) arg = -1e30f;
                    rs[r] += exp2f(arg);
                }
            }
        }
        // row sums: reduce the 16 lanes sharing lhi; one atomic per (mi, r)
        #pragma unroll
        for (int r = 0; r < 4; ++r) {
            float v = rs[r];
            v += __shfl_xor(v, 1);
            v += __shfl_xor(v, 2);
            v += __shfl_xor(v, 4);
            v += __shfl_xor(v, 8);
            if (l15 == 0) atomicAdd(&rowsum_g[growb + r], v);
        }
    }
    // column sums (symmetry): only FULL halves contribute
    if (m0 == WM_FULL) {
        #pragma unroll
        for (int ni = 0; ni < 4; ++ni) {
            float c = colsum[ni];
            c += __shfl_xor(c, 16);
            c += __shfl_xor(c, 32);
            if (lhi == 0) atomicAdd(&rowsum_g[colB + ni * 16 + l15], c);
        }
    }
    if (m1 == WM_FULL) {
        #pragma unroll
        for (int ni = 4; ni < 8; ++ni) {
            float c = colsum[ni];
            c += __shfl_xor(c, 16);
            c += __shfl_xor(c, 32);
            if (lhi == 0) atomicAdd(&rowsum_g[colB + ni * 16 + l15], c);
        }
    }
#undef LOADAB
#undef MFMAAB
}

// ---------------- K3: loss = mean(ln(rowsum)) - mean(pos), single block ----------------
__global__ __launch_bounds__(1024) void k_finalize(const float* __restrict__ rowsum_g,
                                                   const float* __restrict__ pos,
                                                   float* __restrict__ out) {
    const int t = threadIdx.x;
    float l = 0.0f, p = 0.0f;
    #pragma unroll
    for (int q = 0; q < N_ROWS / 1024; ++q) l += logf(rowsum_g[t + q * 1024]);
    #pragma unroll
    for (int q = 0; q < B_ROWS / 1024; ++q) p += pos[t + q * 1024];
    #pragma unroll
    for (int off = 1; off < 64; off <<= 1) {
        l += __shfl_xor(l, off);
        p += __shfl_xor(p, off);
    }
    __shared__ float red[2][16];
    if ((t & 63) == 0) { red[0][t >> 6] = l; red[1][t >> 6] = p; }
    __syncthreads();
    if (t == 0) {
        float L = 0.0f, P = 0.0f;
        #pragma unroll
        for (int q = 0; q < 16; ++q) { L += red[0][q]; P += red[1][q]; }
        out[0] = (L - P) * (1.0f / (float)N_ROWS);
    }
}

extern "C" void kernel_launch(void* const* d_in, const int* in_sizes, int n_in,
                              void* d_out, int out_size, void* d_ws, size_t ws_size,
                              hipStream_t stream) {
    (void)in_sizes; (void)n_in; (void)out_size; (void)ws_size;
    const float* zi = (const float*)d_in[0];
    const float* zj = (const float*)d_in[1];

    // workspace layout
    const size_t ZN_BYTES = (size_t)N_ROWS * D_DIM;  // 4 MiB fp8 (hp-tiled)
    unsigned char* Zn     = (unsigned char*)d_ws;
    float* rowsum_g       = (float*)((char*)d_ws + ZN_BYTES);              // 8192 f32
    float* pos            = (float*)((char*)d_ws + ZN_BYTES + N_ROWS * 4); // 4096 f32

    k_normalize<<<B_ROWS / 4, 256, 0, stream>>>(zi, zj, Zn, pos, rowsum_g);
    k_gemm_lse<<<NBLK, 64, 0, stream>>>(Zn, rowsum_g);
    k_finalize<<<1, 1024, 0, stream>>>(rowsum_g, pos, (float*)d_out);
}